// Round 1
// baseline (627.418 us; speedup 1.0000x reference)
//
#include <hip/hip_runtime.h>

#define TSEQ 512

typedef _Float16 half8 __attribute__((ext_vector_type(8)));
typedef __attribute__((ext_vector_type(4))) float f32x4;

#define MFMAH(a,b,c) __builtin_amdgcn_mfma_f32_16x16x32_f16(a,b,c,0,0,0)

static __device__ __forceinline__ float sigm(float x){ return __builtin_amdgcn_rcpf(1.0f + __expf(-x)); }
static __device__ __forceinline__ float tanh_f(float x){ return 1.0f - 2.0f*__builtin_amdgcn_rcpf(__expf(2.0f*x)+1.0f); }

static __device__ __forceinline__ short f2h(float v){
  union { _Float16 h; short s; } u; u.h = (_Float16)v; return u.s;
}

// wait lgkmcnt(0) only (vmcnt left alone so x-prefetch stays in flight)
static __device__ __forceinline__ void lds_drain(){
  __builtin_amdgcn_s_waitcnt(0xC07F);
  __asm__ __volatile__("" ::: "memory");
}

// raw workgroup barrier WITHOUT the implicit vmcnt(0) drain of __syncthreads.
// callers must lds_drain() first so LDS writes are visible to other waves.
static __device__ __forceinline__ void bar(){
  __asm__ __volatile__("" ::: "memory");
  __builtin_amdgcn_s_barrier();
  __asm__ __volatile__("" ::: "memory");
}

// 512 WGs x 512 thr (8 waves, 2/SIMD per WG; 2 WGs/CU -> 4 waves/SIMD).
// WG owns batch rows [2b, 2b+2). Two co-resident WGs are INDEPENDENT
// recurrence chains: their barrier/LDS-latency stalls interleave, filling
// the ~65% idle pipe slots the single-WG lockstep version exposed.
// Rows 2-3 of the 16-row MFMA tile / cell lanes lq>=2 compute garbage
// (clamped x reads, never stored) -- identical instruction count to the
// 4-row version, so per-WG cost is unchanged.
// Wave wv: gemm gm=wv>>2 (0: layer0 -> gates0(i+1); 1: layer1 -> gates1(i)),
// j-quarter p=wv&3, tiles q=0..3 (gate index) at cols q*64+16p+lr.
// fp16 weights as B-frags in 64 VGPRs; bias folded into MFMA C operand.
// Activations fp16 in LDS, frag-ordered, double-buffered, ONE raw
// s_barrier/step (lgkm-only drain: x-prefetch vmcnt stays in flight).
// Gate redistribution: in-wave LDS roundtrip (masked b128 writes [q][j][m],
// conflict-free b32 reads), no bpermute, no extra barrier.
// act arrs: 0,1 x buf0/1; 2,3 h0 buf0/1; 4,5 h1 buf0/1.
// A-frag offset for lane (lq,lr), chunk F: F*128 + lq*32 + lr*8 (shorts).
extern "C" __global__ void __launch_bounds__(512, 4)
lstm_h16c(const float* __restrict__ x,
          const float* __restrict__ wih0, const float* __restrict__ whh0,
          const float* __restrict__ bih0, const float* __restrict__ bhh0,
          const float* __restrict__ wih1, const float* __restrict__ whh1,
          const float* __restrict__ bih1, const float* __restrict__ bhh1,
          const float* __restrict__ fcw,  const float* __restrict__ fcb,
          float* __restrict__ out)
{
  __shared__ __align__(16) short act[6][256];
  __shared__ __align__(16) float gbuf[2][1024];   // [gemm][q*256 + j*4 + m]
  __shared__ float fcpart[16];

  const int tid = threadIdx.x;
  const int wv  = tid >> 6;
  const int gm  = wv >> 2;
  const int p   = wv & 3;
  const int ln  = tid & 63;
  const int lq  = ln >> 4;
  const int lr  = ln & 15;
  const int b0  = blockIdx.x << 1;               // 2 batch rows per WG
  const int jc  = (p << 4) + lr;                 // j (0..63): gemm col / cell col
  // h/x staging slot for cell thread (k=jc, m=lq):
  const int si  = (((jc>>5)*4 + ((jc>>3)&3))*4 + lq)*8 + (jc&7);
  // A-frag read offset for chunk F=0 (F adds +128): shorts
  const int foff = lq*32 + lr*8;
  float* const gme = &gbuf[gm][0];
  const bool wlane = (lq == 0);

  // ---- one-time: fp16 weight B-frags [op][F][q] = 64 VGPR ----
  half8 W[2][2][4];
  {
    const float* w_op[2] = { gm ? wih1 : wih0, gm ? whh1 : whh0 };
#pragma unroll
    for (int op = 0; op < 2; ++op)
#pragma unroll
      for (int F = 0; F < 2; ++F)
#pragma unroll
        for (int q = 0; q < 4; ++q){
          const float* src = w_op[op] + ((q<<6) + jc)*64 + F*32 + lq*8;
#pragma unroll
          for (int e = 0; e < 8; ++e)
            W[op][F][q][e] = (_Float16)src[e];
        }
  }
  // bias in C operand: Bq[q] = broadcast(bias_q(jc))
  f32x4 Bq[4];
  {
    const float* bi = gm ? bih1 : bih0;
    const float* bh = gm ? bhh1 : bhh0;
#pragma unroll
    for (int q = 0; q < 4; ++q){
      float b = bi[(q<<6)+jc] + bh[(q<<6)+jc];
      Bq[q][0] = b; Bq[q][1] = b; Bq[q][2] = b; Bq[q][3] = b;
    }
  }

  // rows 2-3 of the tile are garbage; clamp their x reads in-bounds
  const int xrow = (lq < 2) ? (b0 + lq) : b0;
  const float* xq = x + (size_t)xrow*(TSEQ*64) + jc;

  float cst = 0.f, hval = 0.f, xv = 0.f;
  half8 aF[4];   // persistent frag regs (masked loads leave lr>=4 lanes stale: harmless rows 4-15)
#pragma unroll
  for (int f = 0; f < 4; ++f) aF[f] = (half8){0,0,0,0,0,0,0,0};

  // ---- prologue ----
  for (int idx = tid; idx < 2*256; idx += 512) act[4 + (idx>>8)][idx & 255] = 0;
  if (gm == 0){
    act[0][si] = f2h(xq[0]);     // x(0) -> buf0
    act[1][si] = f2h(xq[64]);    // x(1) -> buf1
    xv = xq[128];                // x(2)
  }
  __syncthreads();

  if (gm == 0){   // gates0(0) = x(0)·Wih0 + bias (h0(-1)=0) -> cell0 -> h0(0) buf0
    if (lr < 4){
      aF[0] = *(const half8*)(&act[0][0] + foff);
      aF[1] = *(const half8*)(&act[0][0] + foff + 128);
    }
    f32x4 acc[4];
#pragma unroll
    for (int q = 0; q < 4; ++q){
      acc[q] = MFMAH(aF[0], W[0][0][q], Bq[q]);
      acc[q] = MFMAH(aF[1], W[0][1][q], acc[q]);
    }
    if (wlane){
#pragma unroll
      for (int q = 0; q < 4; ++q) *(f32x4*)&gme[q*256 + jc*4] = acc[q];
    }
    lds_drain();
    float gi = sigm  (gme[0*256 + jc*4 + lq]);
    float gf = sigm  (gme[1*256 + jc*4 + lq]);
    float gg = tanh_f(gme[2*256 + jc*4 + lq]);
    float go = sigm  (gme[3*256 + jc*4 + lq]);
    cst  = gf*cst + gi*gg;
    hval = go * tanh_f(cst);
    act[2][si] = f2h(hval);
  }
  __syncthreads();

  // ---- main loops: divergent by gemm, ONE raw barrier per iteration each ----
  if (gm == 1){
#pragma unroll 2
    for (int i = 0; i < TSEQ; ++i){
      const int cb = i & 1, nb = cb ^ 1;
      // gates1(i) = h0(i)·Wih1 + h1(i-1)·Whh1 + bias
      if (lr < 4){
        aF[0] = *(const half8*)(&act[2+cb][0] + foff);
        aF[1] = *(const half8*)(&act[2+cb][0] + foff + 128);
        aF[2] = *(const half8*)(&act[4+nb][0] + foff);
        aF[3] = *(const half8*)(&act[4+nb][0] + foff + 128);
      }
      f32x4 acc[4];
#pragma unroll
      for (int q = 0; q < 4; ++q){
        acc[q] = MFMAH(aF[0], W[0][0][q], Bq[q]);
        acc[q] = MFMAH(aF[1], W[0][1][q], acc[q]);
        acc[q] = MFMAH(aF[2], W[1][0][q], acc[q]);
        acc[q] = MFMAH(aF[3], W[1][1][q], acc[q]);
      }
      if (wlane){
#pragma unroll
        for (int q = 0; q < 4; ++q) *(f32x4*)&gme[q*256 + jc*4] = acc[q];
      }
      lds_drain();
      float gi = sigm  (gme[0*256 + jc*4 + lq]);
      float gf = sigm  (gme[1*256 + jc*4 + lq]);
      float gg = tanh_f(gme[2*256 + jc*4 + lq]);
      float go = sigm  (gme[3*256 + jc*4 + lq]);
      cst  = gf*cst + gi*gg;
      hval = go * tanh_f(cst);
      act[4+cb][si] = f2h(hval);     // h1(i)
      lds_drain();
      bar();
    }
  } else {
#pragma unroll 2
    for (int i = 0; i < TSEQ; ++i){
      const int cb = i & 1, nb = cb ^ 1;
      if (i < TSEQ-1){
        // gates0(i+1) = x(i+1)·Wih0 + h0(i)·Whh0 + bias
        if (lr < 4){
          aF[0] = *(const half8*)(&act[0+nb][0] + foff);
          aF[1] = *(const half8*)(&act[0+nb][0] + foff + 128);
          aF[2] = *(const half8*)(&act[2+cb][0] + foff);
          aF[3] = *(const half8*)(&act[2+cb][0] + foff + 128);
        }
        f32x4 acc[4];
#pragma unroll
        for (int q = 0; q < 4; ++q){
          acc[q] = MFMAH(aF[0], W[0][0][q], Bq[q]);
          acc[q] = MFMAH(aF[1], W[0][1][q], acc[q]);
          acc[q] = MFMAH(aF[2], W[1][0][q], acc[q]);
          acc[q] = MFMAH(aF[3], W[1][1][q], acc[q]);
        }
        if (wlane){
#pragma unroll
          for (int q = 0; q < 4; ++q) *(f32x4*)&gme[q*256 + jc*4] = acc[q];
        }
        lds_drain();
        float gi = sigm  (gme[0*256 + jc*4 + lq]);
        float gf = sigm  (gme[1*256 + jc*4 + lq]);
        float gg = tanh_f(gme[2*256 + jc*4 + lq]);
        float go = sigm  (gme[3*256 + jc*4 + lq]);
        cst  = gf*cst + gi*gg;
        hval = go * tanh_f(cst);
        act[2+nb][si] = f2h(hval);   // h0(i+1)
        if (i < TSEQ-2) act[0+cb][si] = f2h(xv);   // stage x(i+2)
        int tn = i + 3; if (tn > TSEQ-1) tn = TSEQ-1;
        xv = xq[tn << 6];            // prefetch x(i+3)
      }
      lds_drain();
      bar();
    }
  }

  // ---- FC head: gemm1 waves hold h1(T-1) for (m=lq, j=jc) ----
  if (gm == 1){
    float v = hval * fcw[jc];
    v += __shfl_xor(v, 1); v += __shfl_xor(v, 2);
    v += __shfl_xor(v, 4); v += __shfl_xor(v, 8);
    if (lr == 0) fcpart[p*4 + lq] = v;
  }
  __syncthreads();
  if (tid < 2)
    out[b0 + tid] = fcpart[tid] + fcpart[4+tid] + fcpart[8+tid] + fcpart[12+tid] + fcb[0];
}

extern "C" void kernel_launch(void* const* d_in, const int* in_sizes, int n_in,
                              void* d_out, int out_size, void* d_ws, size_t ws_size,
                              hipStream_t stream) {
  const float* x    = (const float*)d_in[0];
  const float* wih0 = (const float*)d_in[1];
  const float* whh0 = (const float*)d_in[2];
  const float* bih0 = (const float*)d_in[3];
  const float* bhh0 = (const float*)d_in[4];
  const float* wih1 = (const float*)d_in[5];
  const float* whh1 = (const float*)d_in[6];
  const float* bih1 = (const float*)d_in[7];
  const float* bhh1 = (const float*)d_in[8];
  const float* fcw  = (const float*)d_in[9];
  const float* fcb  = (const float*)d_in[10];
  float* out = (float*)d_out;

  hipLaunchKernelGGL(lstm_h16c, dim3(512), dim3(512), 0, stream,
                     x, wih0, whh0, bih0, bhh0, wih1, whh1, bih1, bhh1, fcw, fcb, out);
}